// Round 1
// baseline (2363.828 us; speedup 1.0000x reference)
//
#include <hip/hip_runtime.h>
#include <hip/hip_bf16.h>
#include <math.h>

// ---------------- dims ----------------
#define B_     8
#define L_     1024
#define BL_    8192          // B*L
#define C_IN_  12
#define DM_    128           // D_MODEL
#define DS_    16            // D_STATE
#define DC_    4             // D_CONV
#define DI_    256           // D_INNER
#define DTR_   8             // DT_RANK
#define NH_    4             // heads
#define HD_    32            // head dim
#define LH_    128           // LSTM_H
#define FCH_   128
#define NCLS_  5

// ---------------- workspace layout (floats) ----------------
// total 16,386,048 floats = 65.6 MB
#define OFF_U      0u
#define OFF_XC     1048576u
#define OFF_DBL    3145728u
#define OFF_DELTA  3670016u
#define OFF_YG     5767168u
#define OFF_XZ     7864320u     // later: xg ; later AO0/AO1/T0/T1
#define OFF_HM     12058624u
#define OFF_HL     13107200u
#define OFF_WPK    14155776u    // WL(49152) WM(49152) bL(384) bM(384)
#define OFF_HLU    14286848u
#define OFF_HMU    15335424u
#define OFF_POOL   16384000u
// aliases (regions dead by the time they are reused):
#define OFF_PL     0u           // 8192*384 = 3,145,728 (over u,xc)
#define OFF_PM     3145728u     // (over dbl,delta,yg-head)
#define OFF_AO0    7864320u     // (over xg)
#define OFF_AO1    8912896u
#define OFF_T0     9961472u
#define OFF_T1     11010048u

static __device__ __forceinline__ float sigmf(float x){ return 1.f/(1.f+expf(-x)); }
static __device__ __forceinline__ float siluf(float x){ return x/(1.f+expf(-x)); }
static __device__ __forceinline__ float softplusf(float x){
  return (x > 0.f) ? x + log1pf(expf(-x)) : log1pf(expf(x));
}

// ---------------- generic tiled fp32 GEMM ----------------
// C[M x N] = act(A[M x K (row stride lda)] @ W[K x N] + bias)
// grid: (ceil(N/64), M/64), block 256.  act: 0 none, 1 softplus
__global__ __launch_bounds__(256) void gemm_kernel(
    const float* __restrict__ A, int lda,
    const float* __restrict__ W,
    const float* __restrict__ bias,
    float* __restrict__ C,
    int M, int N, int K, int act)
{
  __shared__ float As[64][17];
  __shared__ float Ws[16][65];
  const int tid = threadIdx.x;
  const int tx = tid & 15, ty = tid >> 4;
  const int m0 = blockIdx.y * 64, n0 = blockIdx.x * 64;
  float acc[4][4];
  #pragma unroll
  for (int i=0;i<4;i++)
    #pragma unroll
    for (int j=0;j<4;j++) acc[i][j]=0.f;

  for (int k0=0;k0<K;k0+=16){
    const int ar = tid >> 2, ac4 = (tid & 3) * 4;
    #pragma unroll
    for (int j=0;j<4;j++){
      int kk = k0 + ac4 + j;
      As[ar][ac4+j] = (kk < K) ? A[(size_t)(m0+ar)*lda + kk] : 0.f;
    }
    const int wc = tid & 63, wr0 = (tid >> 6) * 4;
    #pragma unroll
    for (int j=0;j<4;j++){
      int kk = k0 + wr0 + j;
      Ws[wr0+j][wc] = (kk < K && (n0+wc) < N) ? W[(size_t)kk*N + n0 + wc] : 0.f;
    }
    __syncthreads();
    #pragma unroll
    for (int kk=0;kk<16;kk++){
      float a[4], w[4];
      #pragma unroll
      for (int i=0;i<4;i++) a[i] = As[ty*4+i][kk];
      #pragma unroll
      for (int j=0;j<4;j++) w[j] = Ws[kk][tx*4+j];
      #pragma unroll
      for (int i=0;i<4;i++)
        #pragma unroll
        for (int j=0;j<4;j++)
          acc[i][j] = fmaf(a[i], w[j], acc[i][j]);
    }
    __syncthreads();
  }
  #pragma unroll
  for (int i=0;i<4;i++){
    int m = m0 + ty*4 + i;
    #pragma unroll
    for (int j=0;j<4;j++){
      int n = n0 + tx*4 + j;
      if (n < N){
        float v = acc[i][j] + (bias ? bias[n] : 0.f);
        if (act == 1) v = softplusf(v);
        C[(size_t)m*N + n] = v;
      }
    }
  }
}

// ---------------- causal depthwise conv(4) + silu ----------------
__global__ __launch_bounds__(256) void conv_silu_kernel(
    const float* __restrict__ xz, const float* __restrict__ conv_w,
    const float* __restrict__ conv_b, float* __restrict__ xc)
{
  int idx = blockIdx.x * 256 + threadIdx.x;           // over BL_*DI_
  if (idx >= BL_*DI_) return;
  int d = idx & (DI_-1);
  int bl = idx >> 8;                                   // DI_=256
  int l = bl & (L_-1), b = bl >> 10;
  float acc = conv_b[d];
  #pragma unroll
  for (int k=0;k<DC_;k++){
    int lk = l - (DC_-1) + k;
    if (lk >= 0)
      acc = fmaf(xz[((size_t)((b<<10)|lk))*512 + d], conv_w[d*DC_+k], acc);
  }
  xc[idx] = siluf(acc);
}

// ---------------- fused selective-scan + gating ----------------
// grid (16, 8) ; block 256 = 16 d x 16 s
__global__ __launch_bounds__(256) void scan_kernel(
    const float* __restrict__ delta, const float* __restrict__ dbl,
    const float* __restrict__ xc, const float* __restrict__ xz,
    const float* __restrict__ A_log, const float* __restrict__ Dp,
    float* __restrict__ yg)
{
  const int tid = threadIdx.x;
  const int s = tid & 15, dl = tid >> 4;
  const int d = blockIdx.x * 16 + dl;
  const int b = blockIdx.y;
  const float A = -expf(A_log[d*DS_ + s]);
  const float Dv = Dp[d];
  float h = 0.f;
  const size_t base = (size_t)b * L_;
  float dlt = delta[base*256 + d];
  float xcv = xc[base*256 + d];
  float Bv  = dbl[base*40 + DTR_ + s];
  float Cv  = dbl[base*40 + DTR_ + DS_ + s];
  float zv  = xz[base*512 + 256 + d];
  for (int t=0;t<L_;t++){
    float dlt_n=0.f, xcv_n=0.f, Bv_n=0.f, Cv_n=0.f, zv_n=0.f;
    if (t < L_-1){
      size_t r = base + t + 1;
      dlt_n = delta[r*256 + d];
      xcv_n = xc[r*256 + d];
      Bv_n  = dbl[r*40 + DTR_ + s];
      Cv_n  = dbl[r*40 + DTR_ + DS_ + s];
      zv_n  = xz[r*512 + 256 + d];
    }
    h = fmaf(expf(dlt*A), h, (dlt*Bv)*xcv);
    float p = h * Cv;
    p += __shfl_xor(p,1); p += __shfl_xor(p,2);
    p += __shfl_xor(p,4); p += __shfl_xor(p,8);
    if (s == 0){
      size_t r = base + t;
      float y = p + Dv * xcv;
      yg[r*256 + d] = y * siluf(zv);
    }
    dlt=dlt_n; xcv=xcv_n; Bv=Bv_n; Cv=Cv_n; zv=zv_n;
  }
}

// ---------------- persistent LSTM ----------------
// grid 8 (one block per batch), block 1024 = 512 gates x 2 K-halves
__global__ __launch_bounds__(1024) void lstm_kernel(
    const float* __restrict__ xg, const float* __restrict__ w_hh,
    float* __restrict__ HL)
{
  const int b = blockIdx.x;
  const int tid = threadIdx.x;
  const int gate = tid & 511, half = tid >> 9;
  float w[64];
  #pragma unroll
  for (int j=0;j<64;j++) w[j] = w_hh[(size_t)(half*64 + j)*512 + gate];
  __shared__ __align__(16) float h_s[128];
  __shared__ float c_s[128];
  __shared__ float part[1024];
  if (tid < 128){ h_s[tid]=0.f; c_s[tid]=0.f; }
  __syncthreads();
  const float* xgb = xg + (size_t)b * L_ * 512;
  float* HLb = HL + (size_t)b * L_ * 128;
  for (int t=0;t<L_;t++){
    float xv0=0,xv1=0,xv2=0,xv3=0;
    if (tid < 128){
      xv0 = xgb[t*512 + tid];
      xv1 = xgb[t*512 + 128 + tid];
      xv2 = xgb[t*512 + 256 + tid];
      xv3 = xgb[t*512 + 384 + tid];
    }
    float a0=0,a1=0,a2=0,a3=0;
    const float4* h4 = (const float4*)(h_s + half*64);
    #pragma unroll
    for (int j=0;j<16;j++){
      float4 hv = h4[j];
      a0 = fmaf(hv.x, w[4*j+0], a0);
      a1 = fmaf(hv.y, w[4*j+1], a1);
      a2 = fmaf(hv.z, w[4*j+2], a2);
      a3 = fmaf(hv.w, w[4*j+3], a3);
    }
    part[half*512 + gate] = (a0+a1)+(a2+a3);
    __syncthreads();
    if (tid < 128){
      float gi = xv0 + part[tid]       + part[512+tid];
      float gf = xv1 + part[128+tid]   + part[640+tid];
      float gg = xv2 + part[256+tid]   + part[768+tid];
      float go = xv3 + part[384+tid]   + part[896+tid];
      float c = sigmf(gf)*c_s[tid] + sigmf(gi)*tanhf(gg);
      float h = sigmf(go)*tanhf(c);
      c_s[tid] = c; h_s[tid] = h;
      HLb[t*128 + tid] = h;
    }
    __syncthreads();
  }
}

// ---------------- pack attention QKV weights ----------------
// WL = [w00 | w11 | w12]  (for H_L),  WM = [w01 | w02 | w10]  (for H_M)
__global__ __launch_bounds__(256) void pack_kernel(
    const float* __restrict__ ca_w, const float* __restrict__ ca_b,
    float* __restrict__ wpk)
{
  int idx = blockIdx.x * 256 + threadIdx.x;  // 0..49151
  if (idx >= 49152) return;
  int in = idx / 384, c = idx % 384;
  int seg = c >> 7, o = c & 127;
  int dL = (seg==0)?0:1;
  int iL = (seg==0)?0:((seg==1)?1:2);
  int dM = (seg==2)?1:0;
  int iM = (seg==0)?1:((seg==1)?2:0);
  wpk[idx]         = ca_w[(((size_t)(dL*4+iL))*128 + in)*128 + o];
  wpk[49152 + idx] = ca_w[(((size_t)(dM*4+iM))*128 + in)*128 + o];
  if (in == 0){
    wpk[98304 + c] = ca_b[(dL*4+iL)*128 + o];
    wpk[98688 + c] = ca_b[(dM*4+iM)*128 + o];
  }
}

// ---------------- fused flash attention (both directions) ----------------
// grid (4, 32, 2): qtile, b*4+h, dir ; block 256 (one q row / thread)
__global__ __launch_bounds__(256) void attn_kernel(
    const float* __restrict__ PL, const float* __restrict__ PM,
    float* __restrict__ AO)
{
  const int tid = threadIdx.x;
  const int dir = blockIdx.z;
  const int bh = blockIdx.y;
  const int b = bh >> 2, hh = bh & 3;
  const int q = blockIdx.x * 256 + tid;
  const float* Qb; const float* Kb; const float* Vb;
  if (dir == 0){ Qb = PL;       Kb = PM;       Vb = PM + 128; }
  else         { Qb = PM + 256; Kb = PL + 128; Vb = PL + 256; }
  const size_t rowb = (size_t)b * L_;
  float qv[32];
  const float* qp = Qb + (rowb + q)*384 + hh*32;
  #pragma unroll
  for (int j=0;j<32;j++) qv[j] = qp[j];
  __shared__ float Kt[64][33];
  __shared__ float Vt[64][33];
  float o[32];
  #pragma unroll
  for (int j=0;j<32;j++) o[j]=0.f;
  float m = -1e30f, l = 0.f;
  const float scale = 0.17677669529663687f;  // 1/sqrt(32)
  for (int k0=0;k0<L_;k0+=64){
    __syncthreads();
    for (int i=tid;i<2048;i+=256){
      int r = i >> 5, c = i & 31;
      Kt[r][c] = Kb[(rowb + k0 + r)*384 + hh*32 + c];
      Vt[r][c] = Vb[(rowb + k0 + r)*384 + hh*32 + c];
    }
    __syncthreads();
    for (int kk=0;kk<64;kk++){
      float s_ = 0.f;
      #pragma unroll
      for (int j=0;j<32;j++) s_ = fmaf(qv[j], Kt[kk][j], s_);
      s_ *= scale;
      if (s_ > m){
        float corr = expf(m - s_);
        l *= corr;
        #pragma unroll
        for (int j=0;j<32;j++) o[j] *= corr;
        m = s_;
      }
      float p = expf(s_ - m);
      l += p;
      #pragma unroll
      for (int j=0;j<32;j++) o[j] = fmaf(p, Vt[kk][j], o[j]);
    }
  }
  float inv = 1.f / l;
  float* op = AO + (size_t)dir*BL_*128 + (rowb + q)*128 + hh*32;
  #pragma unroll
  for (int j=0;j<32;j++) op[j] = o[j]*inv;
}

// ---------------- residual + LayerNorm ----------------
// grid (8192, 2), block 64 (one wave per row, 2 elems/lane)
__global__ __launch_bounds__(64) void ln_kernel(
    const float* __restrict__ HL, const float* __restrict__ T0,
    const float* __restrict__ HM, const float* __restrict__ T1,
    const float* __restrict__ ln_g, const float* __restrict__ ln_b,
    float* __restrict__ HLu, float* __restrict__ HMu)
{
  const int row = blockIdx.x;
  const int which = blockIdx.y;   // 0: H_Lu , 1: H_Mu
  const float* X = which ? HM : HL;
  const float* T = which ? T1 : T0;
  const float* g = ln_g + which*128;
  const float* bb = ln_b + which*128;
  float* O = which ? HMu : HLu;
  const int lane = threadIdx.x;
  float v0 = X[(size_t)row*128 + lane]      + T[(size_t)row*128 + lane];
  float v1 = X[(size_t)row*128 + 64 + lane] + T[(size_t)row*128 + 64 + lane];
  float s = v0 + v1, s2 = v0*v0 + v1*v1;
  #pragma unroll
  for (int off=1; off<64; off<<=1){ s += __shfl_xor(s,off); s2 += __shfl_xor(s2,off); }
  float mean = s * (1.f/128.f);
  float var = s2 * (1.f/128.f) - mean*mean;
  float r = rsqrtf(var + 1e-5f);
  O[(size_t)row*128 + lane]      = (v0 - mean)*r*g[lane]      + bb[lane];
  O[(size_t)row*128 + 64 + lane] = (v1 - mean)*r*g[64+lane]   + bb[64+lane];
}

// ---------------- mean pool ----------------
// grid (2, 8), block 128 ; pooled[b][0:128]=mean H_Mu, [128:256]=mean H_Lu
__global__ __launch_bounds__(128) void pool_kernel(
    const float* __restrict__ HMu, const float* __restrict__ HLu,
    float* __restrict__ pooled)
{
  const int whichhalf = blockIdx.x;   // 0 -> H_Mu, 1 -> H_Lu
  const int b = blockIdx.y;
  const int d = threadIdx.x;
  const float* S = whichhalf ? HLu : HMu;
  float s = 0.f;
  for (int t=0;t<L_;t++) s += S[((size_t)b*L_ + t)*128 + d];
  pooled[b*256 + whichhalf*128 + d] = s * (1.f/1024.f);
}

// ---------------- final MLP ----------------
// grid 8, block 128
__global__ __launch_bounds__(128) void fc_kernel(
    const float* __restrict__ pooled,
    const float* __restrict__ fc1_w, const float* __restrict__ fc1_b,
    const float* __restrict__ fc2_w, const float* __restrict__ fc2_b,
    float* __restrict__ out)
{
  const int b = blockIdx.x;
  const int j = threadIdx.x;
  __shared__ float hid[128];
  float acc = fc1_b[j];
  for (int k=0;k<256;k++) acc = fmaf(pooled[b*256 + k], fc1_w[k*128 + j], acc);
  hid[j] = fmaxf(acc, 0.f);
  __syncthreads();
  if (j < NCLS_){
    float a = fc2_b[j];
    for (int k=0;k<128;k++) a = fmaf(hid[k], fc2_w[k*NCLS_ + j], a);
    out[b*NCLS_ + j] = a;
  }
}

extern "C" void kernel_launch(void* const* d_in, const int* in_sizes, int n_in,
                              void* d_out, int out_size, void* d_ws, size_t ws_size,
                              hipStream_t stream)
{
  const float* x            = (const float*)d_in[0];
  const float* mamba_proj_w = (const float*)d_in[1];
  const float* mamba_proj_b = (const float*)d_in[2];
  const float* in_proj_w    = (const float*)d_in[3];
  const float* conv_w       = (const float*)d_in[4];
  const float* conv_b       = (const float*)d_in[5];
  const float* x_proj_w     = (const float*)d_in[6];
  const float* dt_proj_w    = (const float*)d_in[7];
  const float* dt_proj_b    = (const float*)d_in[8];
  const float* A_log        = (const float*)d_in[9];
  const float* Dp           = (const float*)d_in[10];
  const float* out_proj_w   = (const float*)d_in[11];
  const float* lstm_w_ih    = (const float*)d_in[12];
  const float* lstm_w_hh    = (const float*)d_in[13];
  const float* lstm_b       = (const float*)d_in[14];
  const float* ca_w         = (const float*)d_in[15];
  const float* ca_b         = (const float*)d_in[16];
  const float* ln_g         = (const float*)d_in[17];
  const float* ln_b         = (const float*)d_in[18];
  const float* fc1_w        = (const float*)d_in[19];
  const float* fc1_b        = (const float*)d_in[20];
  const float* fc2_w        = (const float*)d_in[21];
  const float* fc2_b        = (const float*)d_in[22];

  float* ws     = (float*)d_ws;
  float* u      = ws + OFF_U;
  float* xc     = ws + OFF_XC;
  float* dbl    = ws + OFF_DBL;
  float* delta  = ws + OFF_DELTA;
  float* yg     = ws + OFF_YG;
  float* xz     = ws + OFF_XZ;
  float* xg     = ws + OFF_XZ;     // alias (after scan)
  float* HM     = ws + OFF_HM;
  float* HL     = ws + OFF_HL;
  float* wpk    = ws + OFF_WPK;
  float* PLb    = ws + OFF_PL;     // alias (after H_M done)
  float* PMb    = ws + OFF_PM;     // alias
  float* AObase = ws + OFF_AO0;    // alias (after LSTM done)
  float* AO0    = ws + OFF_AO0;
  float* AO1    = ws + OFF_AO1;
  float* T0     = ws + OFF_T0;
  float* T1     = ws + OFF_T1;
  float* HLu    = ws + OFF_HLU;
  float* HMu    = ws + OFF_HMU;
  float* pooled = ws + OFF_POOL;

  // ---- Mamba branch ----
  gemm_kernel<<<dim3(2,128),256,0,stream>>>(x, 12, mamba_proj_w, mamba_proj_b, u, BL_, 128, 12, 0);
  gemm_kernel<<<dim3(8,128),256,0,stream>>>(u, 128, in_proj_w, nullptr, xz, BL_, 512, 128, 0);
  conv_silu_kernel<<<dim3(BL_*DI_/256),256,0,stream>>>(xz, conv_w, conv_b, xc);
  gemm_kernel<<<dim3(1,128),256,0,stream>>>(xc, 256, x_proj_w, nullptr, dbl, BL_, 40, 256, 0);
  gemm_kernel<<<dim3(4,128),256,0,stream>>>(dbl, 40, dt_proj_w, dt_proj_b, delta, BL_, 256, DTR_, 1);
  scan_kernel<<<dim3(16,8),256,0,stream>>>(delta, dbl, xc, xz, A_log, Dp, yg);
  gemm_kernel<<<dim3(2,128),256,0,stream>>>(yg, 256, out_proj_w, nullptr, HM, BL_, 128, 256, 0);

  // ---- LSTM branch (xg aliases xz: launched after scan consumed z) ----
  gemm_kernel<<<dim3(8,128),256,0,stream>>>(x, 12, lstm_w_ih, lstm_b, xg, BL_, 512, 12, 0);
  lstm_kernel<<<dim3(8),1024,0,stream>>>(xg, lstm_w_hh, HL);

  // ---- cross attention ----
  pack_kernel<<<dim3(192),256,0,stream>>>(ca_w, ca_b, wpk);
  gemm_kernel<<<dim3(6,128),256,0,stream>>>(HL, 128, wpk,         wpk + 98304, PLb, BL_, 384, 128, 0);
  gemm_kernel<<<dim3(6,128),256,0,stream>>>(HM, 128, wpk + 49152, wpk + 98688, PMb, BL_, 384, 128, 0);
  attn_kernel<<<dim3(4,32,2),256,0,stream>>>(PLb, PMb, AObase);
  gemm_kernel<<<dim3(2,128),256,0,stream>>>(AO0, 128, ca_w + 3*16384, ca_b + 384, T0, BL_, 128, 128, 0);
  gemm_kernel<<<dim3(2,128),256,0,stream>>>(AO1, 128, ca_w + 7*16384, ca_b + 896, T1, BL_, 128, 128, 0);

  // ---- residual + LN, pool, MLP ----
  ln_kernel<<<dim3(8192,2),64,0,stream>>>(HL, T0, HM, T1, ln_g, ln_b, HLu, HMu);
  pool_kernel<<<dim3(2,8),128,0,stream>>>(HMu, HLu, pooled);
  fc_kernel<<<dim3(8),128,0,stream>>>(pooled, fc1_w, fc1_b, fc2_w, fc2_b, (float*)d_out);
}

// Round 2
// 2255.074 us; speedup vs baseline: 1.0482x; 1.0482x over previous
//
#include <hip/hip_runtime.h>
#include <hip/hip_bf16.h>
#include <math.h>

// ---------------- dims ----------------
#define B_     8
#define L_     1024
#define BL_    8192          // B*L
#define C_IN_  12
#define DM_    128
#define DS_    16
#define DC_    4
#define DI_    256
#define DTR_   8
#define NH_    4
#define HD_    32
#define LH_    128
#define FCH_   128
#define NCLS_  5

// ---------------- workspace layout (floats) ----------------
#define OFF_U      0u
#define OFF_XC     1048576u
#define OFF_DBL    3145728u
#define OFF_DELTA  3670016u
#define OFF_YG     5767168u
#define OFF_XZ     7864320u
#define OFF_HM     12058624u
#define OFF_HL     13107200u
#define OFF_WPK    14155776u
#define OFF_HLU    14286848u
#define OFF_HMU    15335424u
#define OFF_POOL   16384000u
#define OFF_PL     0u
#define OFF_PM     3145728u
#define OFF_AO0    7864320u
#define OFF_AO1    8912896u
#define OFF_T0     9961472u
#define OFF_T1     11010048u

static __device__ __forceinline__ float sigmf(float x){ return 1.f/(1.f+expf(-x)); }
static __device__ __forceinline__ float siluf(float x){ return x/(1.f+expf(-x)); }
static __device__ __forceinline__ float softplusf(float x){
  return (x > 0.f) ? x + log1pf(expf(-x)) : log1pf(expf(x));
}
// DPP quad-perm butterfly adds across lane bits 0,1 (VALU, no DS pipe)
static __device__ __forceinline__ float qbcast_xor1(float x){
  return __int_as_float(__builtin_amdgcn_mov_dpp(__float_as_int(x), 0xB1, 0xF, 0xF, true));
}
static __device__ __forceinline__ float qbcast_xor2(float x){
  return __int_as_float(__builtin_amdgcn_mov_dpp(__float_as_int(x), 0x4E, 0xF, 0xF, true));
}

// ---------------- generic tiled fp32 GEMM (small/odd shapes) ----------------
__global__ __launch_bounds__(256) void gemm_kernel(
    const float* __restrict__ A, int lda,
    const float* __restrict__ W,
    const float* __restrict__ bias,
    float* __restrict__ C,
    int M, int N, int K, int act)
{
  __shared__ float As[64][17];
  __shared__ float Ws[16][65];
  const int tid = threadIdx.x;
  const int tx = tid & 15, ty = tid >> 4;
  const int m0 = blockIdx.y * 64, n0 = blockIdx.x * 64;
  float acc[4][4];
  #pragma unroll
  for (int i=0;i<4;i++)
    #pragma unroll
    for (int j=0;j<4;j++) acc[i][j]=0.f;

  for (int k0=0;k0<K;k0+=16){
    const int ar = tid >> 2, ac4 = (tid & 3) * 4;
    #pragma unroll
    for (int j=0;j<4;j++){
      int kk = k0 + ac4 + j;
      As[ar][ac4+j] = (kk < K) ? A[(size_t)(m0+ar)*lda + kk] : 0.f;
    }
    const int wc = tid & 63, wr0 = (tid >> 6) * 4;
    #pragma unroll
    for (int j=0;j<4;j++){
      int kk = k0 + wr0 + j;
      Ws[wr0+j][wc] = (kk < K && (n0+wc) < N) ? W[(size_t)kk*N + n0 + wc] : 0.f;
    }
    __syncthreads();
    #pragma unroll
    for (int kk=0;kk<16;kk++){
      float a[4], w[4];
      #pragma unroll
      for (int i=0;i<4;i++) a[i] = As[ty*4+i][kk];
      #pragma unroll
      for (int j=0;j<4;j++) w[j] = Ws[kk][tx*4+j];
      #pragma unroll
      for (int i=0;i<4;i++)
        #pragma unroll
        for (int j=0;j<4;j++)
          acc[i][j] = fmaf(a[i], w[j], acc[i][j]);
    }
    __syncthreads();
  }
  #pragma unroll
  for (int i=0;i<4;i++){
    int m = m0 + ty*4 + i;
    #pragma unroll
    for (int j=0;j<4;j++){
      int n = n0 + tx*4 + j;
      if (n < N){
        float v = acc[i][j] + (bias ? bias[n] : 0.f);
        if (act == 1) v = softplusf(v);
        C[(size_t)m*N + n] = v;
      }
    }
  }
}

// ---------------- 128x128-tile fp32 GEMM, 8x8/thread, float4 LDS ----------------
// requires M%128==0, N%128==0, K%8==0
__global__ __launch_bounds__(256,2) void gemm128_kernel(
    const float* __restrict__ A, int lda,
    const float* __restrict__ W,
    const float* __restrict__ bias,
    float* __restrict__ C,
    int M, int N, int K, int act)
{
  __shared__ float As[8][132];   // transposed: As[k][m]
  __shared__ float Ws[8][132];
  const int tid = threadIdx.x;
  const int tx = tid & 15, ty = tid >> 4;
  const int m0 = blockIdx.y * 128, n0 = blockIdx.x * 128;
  const int ar = tid >> 1, akq = (tid & 1) * 4;       // A stage: row, k-quad
  const int wkr = tid >> 5, wnc = (tid & 31) * 4;     // W stage: k-row, n-col
  float acc[8][8];
  #pragma unroll
  for (int i=0;i<8;i++)
    #pragma unroll
    for (int j=0;j<8;j++) acc[i][j]=0.f;

  for (int k0=0;k0<K;k0+=8){
    float4 av = *(const float4*)&A[(size_t)(m0+ar)*lda + k0 + akq];
    float4 wv = *(const float4*)&W[(size_t)(k0+wkr)*N + n0 + wnc];
    __syncthreads();
    As[akq+0][ar]=av.x; As[akq+1][ar]=av.y; As[akq+2][ar]=av.z; As[akq+3][ar]=av.w;
    *(float4*)&Ws[wkr][wnc] = wv;
    __syncthreads();
    #pragma unroll
    for (int kk=0;kk<8;kk++){
      float4 a0 = *(const float4*)&As[kk][ty*8];
      float4 a1 = *(const float4*)&As[kk][ty*8+4];
      float4 w0 = *(const float4*)&Ws[kk][tx*8];
      float4 w1 = *(const float4*)&Ws[kk][tx*8+4];
      float a[8] = {a0.x,a0.y,a0.z,a0.w,a1.x,a1.y,a1.z,a1.w};
      float w[8] = {w0.x,w0.y,w0.z,w0.w,w1.x,w1.y,w1.z,w1.w};
      #pragma unroll
      for (int i=0;i<8;i++)
        #pragma unroll
        for (int j=0;j<8;j++)
          acc[i][j] = fmaf(a[i], w[j], acc[i][j]);
    }
  }
  #pragma unroll
  for (int i=0;i<8;i++){
    int m = m0 + ty*8 + i;
    #pragma unroll
    for (int j=0;j<8;j++){
      int n = n0 + tx*8 + j;
      float v = acc[i][j] + (bias ? bias[n] : 0.f);
      if (act == 1) v = softplusf(v);
      C[(size_t)m*N + n] = v;
    }
  }
}

// ---------------- causal depthwise conv(4) + silu ----------------
__global__ __launch_bounds__(256) void conv_silu_kernel(
    const float* __restrict__ xz, const float* __restrict__ conv_w,
    const float* __restrict__ conv_b, float* __restrict__ xc)
{
  int idx = blockIdx.x * 256 + threadIdx.x;
  if (idx >= BL_*DI_) return;
  int d = idx & (DI_-1);
  int bl = idx >> 8;
  int l = bl & (L_-1), b = bl >> 10;
  float acc = conv_b[d];
  #pragma unroll
  for (int k=0;k<DC_;k++){
    int lk = l - (DC_-1) + k;
    if (lk >= 0)
      acc = fmaf(xz[((size_t)((b<<10)|lk))*512 + d], conv_w[d*DC_+k], acc);
  }
  xc[idx] = siluf(acc);
}

// ---------------- fused selective-scan + gating, LDS time-tiled ----------------
// grid (16, 8) ; block 256 = 16 d x 16 s
__global__ __launch_bounds__(256) void scan_kernel(
    const float* __restrict__ delta, const float* __restrict__ dbl,
    const float* __restrict__ xc, const float* __restrict__ xz,
    const float* __restrict__ A_log, const float* __restrict__ Dp,
    float* __restrict__ yg)
{
  const int tid = threadIdx.x;
  const int s = tid & 15, dl = tid >> 4;
  const int d0 = blockIdx.x * 16;
  const int d = d0 + dl;
  const int b = blockIdx.y;
  __shared__ float sd[32][16], sx[32][16], sz[32][16];
  __shared__ float sB[32][17], sC[32][17];
  const float A = -expf(A_log[d*DS_ + s]);
  const float Dv = Dp[d];
  float h = 0.f;
  const size_t base = (size_t)b * L_;
  for (int t0=0; t0<L_; t0+=32){
    __syncthreads();
    #pragma unroll
    for (int i0=0;i0<2;i0++){
      int i = tid + i0*256;
      int tl = i >> 4, e = i & 15;
      size_t r = base + t0 + tl;
      sd[tl][e] = delta[r*256 + d0 + e];
      sx[tl][e] = xc[r*256 + d0 + e];
      sz[tl][e] = xz[r*512 + 256 + d0 + e];
      sB[tl][e] = dbl[r*40 + DTR_ + e];
      sC[tl][e] = dbl[r*40 + DTR_ + DS_ + e];
    }
    __syncthreads();
    for (int j=0;j<32;j++){
      float dlt = sd[j][dl], xcv = sx[j][dl];
      float Bv = sB[j][s], Cv = sC[j][s];
      h = fmaf(expf(dlt*A), h, (dlt*Bv)*xcv);
      float pr = h * Cv;
      pr += qbcast_xor1(pr);
      pr += qbcast_xor2(pr);
      pr += __shfl_xor(pr, 4);
      pr += __shfl_xor(pr, 8);
      if (s == 0){
        float y = pr + Dv * xcv;
        yg[(base + t0 + j)*256 + d] = y * siluf(sz[j][dl]);
      }
    }
  }
}

// ---------------- persistent LSTM, weights in VGPR, DPP reduce ----------------
// grid 8 (one block per batch), block 512: thread = (g:0..127, p:0..3)
__global__ __launch_bounds__(512,2) void lstm_kernel(
    const float* __restrict__ xg, const float* __restrict__ w_hh,
    float* __restrict__ HL)
{
  const int b = blockIdx.x;
  const int tid = threadIdx.x;
  const int g = tid >> 2, p = tid & 3;
  // weights for k in [32p,32p+32), stored rotated so h-reads are bank-staggered:
  // slot jj corresponds to k-quad j = (jj + 2p) & 7
  float wi[32], wf[32], wg_[32], wo[32];
  #pragma unroll
  for (int jj=0;jj<8;jj++){
    const int j = (jj + 2*p) & 7;
    const float* wr = w_hh + (size_t)(32*p + 4*j)*512 + g;
    #pragma unroll
    for (int c=0;c<4;c++){
      wi[4*jj+c]  = wr[(size_t)c*512];
      wf[4*jj+c]  = wr[(size_t)c*512 + 128];
      wg_[4*jj+c] = wr[(size_t)c*512 + 256];
      wo[4*jj+c]  = wr[(size_t)c*512 + 384];
    }
  }
  __shared__ float h_s[2][128];
  if (tid < 128) h_s[0][tid] = 0.f;
  float creg = 0.f;
  const float* xgb = xg + (size_t)b * L_ * 512;
  float* HLb = HL + (size_t)b * L_ * 128;
  float xv0=0,xv1=0,xv2=0,xv3=0;
  if (p == 0){
    xv0 = xgb[g]; xv1 = xgb[128+g]; xv2 = xgb[256+g]; xv3 = xgb[384+g];
  }
  __syncthreads();
  int cur = 0;
  for (int t=0;t<L_;t++){
    const float* hb = h_s[cur] + 32*p;
    float a_i=0,a_f=0,a_g=0,a_o=0;
    #pragma unroll
    for (int jj=0;jj<8;jj++){
      const int j = (jj + 2*p) & 7;     // LDS address only; reg indices static
      float4 hv = *(const float4*)(hb + 4*j);
      a_i = fmaf(hv.x, wi[4*jj+0], a_i);
      a_f = fmaf(hv.x, wf[4*jj+0], a_f);
      a_g = fmaf(hv.x, wg_[4*jj+0], a_g);
      a_o = fmaf(hv.x, wo[4*jj+0], a_o);
      a_i = fmaf(hv.y, wi[4*jj+1], a_i);
      a_f = fmaf(hv.y, wf[4*jj+1], a_f);
      a_g = fmaf(hv.y, wg_[4*jj+1], a_g);
      a_o = fmaf(hv.y, wo[4*jj+1], a_o);
      a_i = fmaf(hv.z, wi[4*jj+2], a_i);
      a_f = fmaf(hv.z, wf[4*jj+2], a_f);
      a_g = fmaf(hv.z, wg_[4*jj+2], a_g);
      a_o = fmaf(hv.z, wo[4*jj+2], a_o);
      a_i = fmaf(hv.w, wi[4*jj+3], a_i);
      a_f = fmaf(hv.w, wf[4*jj+3], a_f);
      a_g = fmaf(hv.w, wg_[4*jj+3], a_g);
      a_o = fmaf(hv.w, wo[4*jj+3], a_o);
    }
    // prefetch next-step x preactivations (hides L2/L3 latency under reduce)
    float xn0=0,xn1=0,xn2=0,xn3=0;
    if (p == 0 && t+1 < L_){
      const float* xr = xgb + (size_t)(t+1)*512;
      xn0 = xr[g]; xn1 = xr[128+g]; xn2 = xr[256+g]; xn3 = xr[384+g];
    }
    // reduce across p (lane bits 0,1) via DPP quad-perm butterflies
    a_i += qbcast_xor1(a_i); a_i += qbcast_xor2(a_i);
    a_f += qbcast_xor1(a_f); a_f += qbcast_xor2(a_f);
    a_g += qbcast_xor1(a_g); a_g += qbcast_xor2(a_g);
    a_o += qbcast_xor1(a_o); a_o += qbcast_xor2(a_o);
    if (p == 0){
      float c = sigmf(a_f + xv1)*creg + sigmf(a_i + xv0)*tanhf(a_g + xv2);
      float hval = sigmf(a_o + xv3)*tanhf(c);
      creg = c;
      h_s[cur^1][g] = hval;
      HLb[t*128 + g] = hval;
    }
    __syncthreads();
    cur ^= 1;
    xv0=xn0; xv1=xn1; xv2=xn2; xv3=xn3;
  }
}

// ---------------- pack attention QKV weights ----------------
__global__ __launch_bounds__(256) void pack_kernel(
    const float* __restrict__ ca_w, const float* __restrict__ ca_b,
    float* __restrict__ wpk)
{
  int idx = blockIdx.x * 256 + threadIdx.x;
  if (idx >= 49152) return;
  int in = idx / 384, c = idx % 384;
  int seg = c >> 7, o = c & 127;
  int dL = (seg==0)?0:1;
  int iL = (seg==0)?0:((seg==1)?1:2);
  int dM = (seg==2)?1:0;
  int iM = (seg==0)?1:((seg==1)?2:0);
  wpk[idx]         = ca_w[(((size_t)(dL*4+iL))*128 + in)*128 + o];
  wpk[49152 + idx] = ca_w[(((size_t)(dM*4+iM))*128 + in)*128 + o];
  if (in == 0){
    wpk[98304 + c] = ca_b[(dL*4+iL)*128 + o];
    wpk[98688 + c] = ca_b[(dM*4+iM)*128 + o];
  }
}

// ---------------- fused flash attention (both directions) ----------------
__global__ __launch_bounds__(256) void attn_kernel(
    const float* __restrict__ PL, const float* __restrict__ PM,
    float* __restrict__ AO)
{
  const int tid = threadIdx.x;
  const int dir = blockIdx.z;
  const int bh = blockIdx.y;
  const int b = bh >> 2, hh = bh & 3;
  const int q = blockIdx.x * 256 + tid;
  const float* Qb; const float* Kb; const float* Vb;
  if (dir == 0){ Qb = PL;       Kb = PM;       Vb = PM + 128; }
  else         { Qb = PM + 256; Kb = PL + 128; Vb = PL + 256; }
  const size_t rowb = (size_t)b * L_;
  float qv[32];
  const float* qp = Qb + (rowb + q)*384 + hh*32;
  #pragma unroll
  for (int j=0;j<32;j++) qv[j] = qp[j];
  __shared__ float Kt[64][33];
  __shared__ float Vt[64][33];
  float o[32];
  #pragma unroll
  for (int j=0;j<32;j++) o[j]=0.f;
  float m = -1e30f, l = 0.f;
  const float scale = 0.17677669529663687f;
  for (int k0=0;k0<L_;k0+=64){
    __syncthreads();
    for (int i=tid;i<2048;i+=256){
      int r = i >> 5, c = i & 31;
      Kt[r][c] = Kb[(rowb + k0 + r)*384 + hh*32 + c];
      Vt[r][c] = Vb[(rowb + k0 + r)*384 + hh*32 + c];
    }
    __syncthreads();
    for (int kk=0;kk<64;kk++){
      float s_ = 0.f;
      #pragma unroll
      for (int j=0;j<32;j++) s_ = fmaf(qv[j], Kt[kk][j], s_);
      s_ *= scale;
      if (s_ > m){
        float corr = expf(m - s_);
        l *= corr;
        #pragma unroll
        for (int j=0;j<32;j++) o[j] *= corr;
        m = s_;
      }
      float p = expf(s_ - m);
      l += p;
      #pragma unroll
      for (int j=0;j<32;j++) o[j] = fmaf(p, Vt[kk][j], o[j]);
    }
  }
  float inv = 1.f / l;
  float* op = AO + (size_t)dir*BL_*128 + (rowb + q)*128 + hh*32;
  #pragma unroll
  for (int j=0;j<32;j++) op[j] = o[j]*inv;
}

// ---------------- residual + LayerNorm ----------------
__global__ __launch_bounds__(64) void ln_kernel(
    const float* __restrict__ HL, const float* __restrict__ T0,
    const float* __restrict__ HM, const float* __restrict__ T1,
    const float* __restrict__ ln_g, const float* __restrict__ ln_b,
    float* __restrict__ HLu, float* __restrict__ HMu)
{
  const int row = blockIdx.x;
  const int which = blockIdx.y;
  const float* X = which ? HM : HL;
  const float* T = which ? T1 : T0;
  const float* g = ln_g + which*128;
  const float* bb = ln_b + which*128;
  float* O = which ? HMu : HLu;
  const int lane = threadIdx.x;
  float v0 = X[(size_t)row*128 + lane]      + T[(size_t)row*128 + lane];
  float v1 = X[(size_t)row*128 + 64 + lane] + T[(size_t)row*128 + 64 + lane];
  float s = v0 + v1, s2 = v0*v0 + v1*v1;
  #pragma unroll
  for (int off=1; off<64; off<<=1){ s += __shfl_xor(s,off); s2 += __shfl_xor(s2,off); }
  float mean = s * (1.f/128.f);
  float var = s2 * (1.f/128.f) - mean*mean;
  float r = rsqrtf(var + 1e-5f);
  O[(size_t)row*128 + lane]      = (v0 - mean)*r*g[lane]      + bb[lane];
  O[(size_t)row*128 + 64 + lane] = (v1 - mean)*r*g[64+lane]   + bb[64+lane];
}

// ---------------- mean pool ----------------
__global__ __launch_bounds__(128) void pool_kernel(
    const float* __restrict__ HMu, const float* __restrict__ HLu,
    float* __restrict__ pooled)
{
  const int whichhalf = blockIdx.x;
  const int b = blockIdx.y;
  const int d = threadIdx.x;
  const float* S = whichhalf ? HLu : HMu;
  float s = 0.f;
  for (int t=0;t<L_;t++) s += S[((size_t)b*L_ + t)*128 + d];
  pooled[b*256 + whichhalf*128 + d] = s * (1.f/1024.f);
}

// ---------------- final MLP ----------------
__global__ __launch_bounds__(128) void fc_kernel(
    const float* __restrict__ pooled,
    const float* __restrict__ fc1_w, const float* __restrict__ fc1_b,
    const float* __restrict__ fc2_w, const float* __restrict__ fc2_b,
    float* __restrict__ out)
{
  const int b = blockIdx.x;
  const int j = threadIdx.x;
  __shared__ float hid[128];
  float acc = fc1_b[j];
  for (int k=0;k<256;k++) acc = fmaf(pooled[b*256 + k], fc1_w[k*128 + j], acc);
  hid[j] = fmaxf(acc, 0.f);
  __syncthreads();
  if (j < NCLS_){
    float a = fc2_b[j];
    for (int k=0;k<128;k++) a = fmaf(hid[k], fc2_w[k*NCLS_ + j], a);
    out[b*NCLS_ + j] = a;
  }
}

extern "C" void kernel_launch(void* const* d_in, const int* in_sizes, int n_in,
                              void* d_out, int out_size, void* d_ws, size_t ws_size,
                              hipStream_t stream)
{
  const float* x            = (const float*)d_in[0];
  const float* mamba_proj_w = (const float*)d_in[1];
  const float* mamba_proj_b = (const float*)d_in[2];
  const float* in_proj_w    = (const float*)d_in[3];
  const float* conv_w       = (const float*)d_in[4];
  const float* conv_b       = (const float*)d_in[5];
  const float* x_proj_w     = (const float*)d_in[6];
  const float* dt_proj_w    = (const float*)d_in[7];
  const float* dt_proj_b    = (const float*)d_in[8];
  const float* A_log        = (const float*)d_in[9];
  const float* Dp           = (const float*)d_in[10];
  const float* out_proj_w   = (const float*)d_in[11];
  const float* lstm_w_ih    = (const float*)d_in[12];
  const float* lstm_w_hh    = (const float*)d_in[13];
  const float* lstm_b       = (const float*)d_in[14];
  const float* ca_w         = (const float*)d_in[15];
  const float* ca_b         = (const float*)d_in[16];
  const float* ln_g         = (const float*)d_in[17];
  const float* ln_b         = (const float*)d_in[18];
  const float* fc1_w        = (const float*)d_in[19];
  const float* fc1_b        = (const float*)d_in[20];
  const float* fc2_w        = (const float*)d_in[21];
  const float* fc2_b        = (const float*)d_in[22];

  float* ws     = (float*)d_ws;
  float* u      = ws + OFF_U;
  float* xc     = ws + OFF_XC;
  float* dbl    = ws + OFF_DBL;
  float* delta  = ws + OFF_DELTA;
  float* yg     = ws + OFF_YG;
  float* xz     = ws + OFF_XZ;
  float* xg     = ws + OFF_XZ;
  float* HM     = ws + OFF_HM;
  float* HL     = ws + OFF_HL;
  float* wpk    = ws + OFF_WPK;
  float* PLb    = ws + OFF_PL;
  float* PMb    = ws + OFF_PM;
  float* AObase = ws + OFF_AO0;
  float* AO0    = ws + OFF_AO0;
  float* AO1    = ws + OFF_AO1;
  float* T0     = ws + OFF_T0;
  float* T1     = ws + OFF_T1;
  float* HLu    = ws + OFF_HLU;
  float* HMu    = ws + OFF_HMU;
  float* pooled = ws + OFF_POOL;

  // ---- Mamba branch ----
  gemm_kernel<<<dim3(2,128),256,0,stream>>>(x, 12, mamba_proj_w, mamba_proj_b, u, BL_, 128, 12, 0);
  gemm128_kernel<<<dim3(4,64),256,0,stream>>>(u, 128, in_proj_w, nullptr, xz, BL_, 512, 128, 0);
  conv_silu_kernel<<<dim3(BL_*DI_/256),256,0,stream>>>(xz, conv_w, conv_b, xc);
  gemm_kernel<<<dim3(1,128),256,0,stream>>>(xc, 256, x_proj_w, nullptr, dbl, BL_, 40, 256, 0);
  gemm128_kernel<<<dim3(2,64),256,0,stream>>>(dbl, 40, dt_proj_w, dt_proj_b, delta, BL_, 256, 8, 1);
  scan_kernel<<<dim3(16,8),256,0,stream>>>(delta, dbl, xc, xz, A_log, Dp, yg);
  gemm128_kernel<<<dim3(1,64),256,0,stream>>>(yg, 256, out_proj_w, nullptr, HM, BL_, 128, 256, 0);

  // ---- LSTM branch ----
  gemm_kernel<<<dim3(8,128),256,0,stream>>>(x, 12, lstm_w_ih, lstm_b, xg, BL_, 512, 12, 0);
  lstm_kernel<<<dim3(8),512,0,stream>>>(xg, lstm_w_hh, HL);

  // ---- cross attention ----
  pack_kernel<<<dim3(192),256,0,stream>>>(ca_w, ca_b, wpk);
  gemm128_kernel<<<dim3(3,64),256,0,stream>>>(HL, 128, wpk,         wpk + 98304, PLb, BL_, 384, 128, 0);
  gemm128_kernel<<<dim3(3,64),256,0,stream>>>(HM, 128, wpk + 49152, wpk + 98688, PMb, BL_, 384, 128, 0);
  attn_kernel<<<dim3(4,32,2),256,0,stream>>>(PLb, PMb, AObase);
  gemm128_kernel<<<dim3(1,64),256,0,stream>>>(AO0, 128, ca_w + 3*16384, ca_b + 384, T0, BL_, 128, 128, 0);
  gemm128_kernel<<<dim3(1,64),256,0,stream>>>(AO1, 128, ca_w + 7*16384, ca_b + 896, T1, BL_, 128, 128, 0);

  // ---- residual + LN, pool, MLP ----
  ln_kernel<<<dim3(8192,2),64,0,stream>>>(HL, T0, HM, T1, ln_g, ln_b, HLu, HMu);
  pool_kernel<<<dim3(2,8),128,0,stream>>>(HMu, HLu, pooled);
  fc_kernel<<<dim3(8),128,0,stream>>>(pooled, fc1_w, fc1_b, fc2_w, fc2_b, (float*)d_out);
}

// Round 3
// 1415.945 us; speedup vs baseline: 1.6694x; 1.5926x over previous
//
#include <hip/hip_runtime.h>
#include <hip/hip_bf16.h>
#include <math.h>

// ---------------- dims ----------------
#define B_     8
#define L_     1024
#define BL_    8192
#define C_IN_  12
#define DM_    128
#define DS_    16
#define DC_    4
#define DI_    256
#define DTR_   8
#define NH_    4
#define HD_    32
#define LH_    128
#define FCH_   128
#define NCLS_  5

// ---------------- workspace layout (floats) ----------------
// phase 1 (mamba+lstm):  u, xc, dbl, delta, yg, xz live in [0..12.06M); xg at 12.06M
// phase 2 (attention):   HL@0, PL, PM, AO0, AO1, T0, T1 all in [0..11.54M) over dead phase-1
#define OFF_U      0u
#define OFF_XC     1048576u
#define OFF_DBL    3145728u
#define OFF_DELTA  3670016u
#define OFF_YG     5767168u
#define OFF_XZ     7864320u     // 8192*512 ends 12058624
#define OFF_XG     12058624u    // 8192*512 ends 16252928 (dead after fused kernel)
#define OFF_HM     12058624u    // written AFTER fused kernel (over dead xg head)
#define OFF_HL     0u           // written by fused kernel (over dead u)
#define OFF_PL     1048576u     // 8192*384 ends 4194304
#define OFF_PM     4194304u     // ends 7340032
#define OFF_AO0    7340032u
#define OFF_AO1    8388608u
#define OFF_T0     9437184u
#define OFF_T1     10485760u    // ends 11534336
#define OFF_WPK    14155776u    // packed after fused kernel (over dead xg)
#define OFF_HLU    14286848u
#define OFF_HMU    15335424u
#define OFF_POOL   16384000u

static __device__ __forceinline__ float fexpf_(float x){ return __builtin_amdgcn_exp2f(x*1.44269504089f); }
static __device__ __forceinline__ float fsig(float x){ return __builtin_amdgcn_rcpf(1.f + fexpf_(-x)); }
static __device__ __forceinline__ float ftanh(float x){ return 1.f - 2.f*__builtin_amdgcn_rcpf(1.f + fexpf_(2.f*x)); }
static __device__ __forceinline__ float siluf(float x){ return x*fsig(x); }
static __device__ __forceinline__ float softplusf(float x){
  return (x > 0.f) ? x + log1pf(expf(-x)) : log1pf(expf(x));
}
static __device__ __forceinline__ float qbcast_xor1(float x){
  return __int_as_float(__builtin_amdgcn_mov_dpp(__float_as_int(x), 0xB1, 0xF, 0xF, true));
}
static __device__ __forceinline__ float qbcast_xor2(float x){
  return __int_as_float(__builtin_amdgcn_mov_dpp(__float_as_int(x), 0x4E, 0xF, 0xF, true));
}

// ---------------- generic tiled fp32 GEMM (small/odd shapes) ----------------
__global__ __launch_bounds__(256) void gemm_kernel(
    const float* __restrict__ A, int lda,
    const float* __restrict__ W,
    const float* __restrict__ bias,
    float* __restrict__ C,
    int M, int N, int K, int act)
{
  __shared__ float As[64][17];
  __shared__ float Ws[16][65];
  const int tid = threadIdx.x;
  const int tx = tid & 15, ty = tid >> 4;
  const int m0 = blockIdx.y * 64, n0 = blockIdx.x * 64;
  float acc[4][4];
  #pragma unroll
  for (int i=0;i<4;i++)
    #pragma unroll
    for (int j=0;j<4;j++) acc[i][j]=0.f;

  for (int k0=0;k0<K;k0+=16){
    const int ar = tid >> 2, ac4 = (tid & 3) * 4;
    #pragma unroll
    for (int j=0;j<4;j++){
      int kk = k0 + ac4 + j;
      As[ar][ac4+j] = (kk < K) ? A[(size_t)(m0+ar)*lda + kk] : 0.f;
    }
    const int wc = tid & 63, wr0 = (tid >> 6) * 4;
    #pragma unroll
    for (int j=0;j<4;j++){
      int kk = k0 + wr0 + j;
      Ws[wr0+j][wc] = (kk < K && (n0+wc) < N) ? W[(size_t)kk*N + n0 + wc] : 0.f;
    }
    __syncthreads();
    #pragma unroll
    for (int kk=0;kk<16;kk++){
      float a[4], w[4];
      #pragma unroll
      for (int i=0;i<4;i++) a[i] = As[ty*4+i][kk];
      #pragma unroll
      for (int j=0;j<4;j++) w[j] = Ws[kk][tx*4+j];
      #pragma unroll
      for (int i=0;i<4;i++)
        #pragma unroll
        for (int j=0;j<4;j++)
          acc[i][j] = fmaf(a[i], w[j], acc[i][j]);
    }
    __syncthreads();
  }
  #pragma unroll
  for (int i=0;i<4;i++){
    int m = m0 + ty*4 + i;
    #pragma unroll
    for (int j=0;j<4;j++){
      int n = n0 + tx*4 + j;
      if (n < N){
        float v = acc[i][j] + (bias ? bias[n] : 0.f);
        if (act == 1) v = softplusf(v);
        C[(size_t)m*N + n] = v;
      }
    }
  }
}

// ---------------- 128x128-tile fp32 GEMM, 8x8/thread ----------------
__global__ __launch_bounds__(256,2) void gemm128_kernel(
    const float* __restrict__ A, int lda,
    const float* __restrict__ W,
    const float* __restrict__ bias,
    float* __restrict__ C,
    int M, int N, int K, int act)
{
  __shared__ float As[8][132];
  __shared__ float Ws[8][132];
  const int tid = threadIdx.x;
  const int tx = tid & 15, ty = tid >> 4;
  const int m0 = blockIdx.y * 128, n0 = blockIdx.x * 128;
  const int ar = tid >> 1, akq = (tid & 1) * 4;
  const int wkr = tid >> 5, wnc = (tid & 31) * 4;
  float acc[8][8];
  #pragma unroll
  for (int i=0;i<8;i++)
    #pragma unroll
    for (int j=0;j<8;j++) acc[i][j]=0.f;

  for (int k0=0;k0<K;k0+=8){
    float4 av = *(const float4*)&A[(size_t)(m0+ar)*lda + k0 + akq];
    float4 wv = *(const float4*)&W[(size_t)(k0+wkr)*N + n0 + wnc];
    __syncthreads();
    As[akq+0][ar]=av.x; As[akq+1][ar]=av.y; As[akq+2][ar]=av.z; As[akq+3][ar]=av.w;
    *(float4*)&Ws[wkr][wnc] = wv;
    __syncthreads();
    #pragma unroll
    for (int kk=0;kk<8;kk++){
      float4 a0 = *(const float4*)&As[kk][ty*8];
      float4 a1 = *(const float4*)&As[kk][ty*8+4];
      float4 w0 = *(const float4*)&Ws[kk][tx*8];
      float4 w1 = *(const float4*)&Ws[kk][tx*8+4];
      float a[8] = {a0.x,a0.y,a0.z,a0.w,a1.x,a1.y,a1.z,a1.w};
      float w[8] = {w0.x,w0.y,w0.z,w0.w,w1.x,w1.y,w1.z,w1.w};
      #pragma unroll
      for (int i=0;i<8;i++)
        #pragma unroll
        for (int j=0;j<8;j++)
          acc[i][j] = fmaf(a[i], w[j], acc[i][j]);
    }
  }
  #pragma unroll
  for (int i=0;i<8;i++){
    int m = m0 + ty*8 + i;
    #pragma unroll
    for (int j=0;j<8;j++){
      int n = n0 + tx*8 + j;
      float v = acc[i][j] + (bias ? bias[n] : 0.f);
      if (act == 1) v = softplusf(v);
      C[(size_t)m*N + n] = v;
    }
  }
}

// ---------------- causal depthwise conv(4) + silu ----------------
__global__ __launch_bounds__(256) void conv_silu_kernel(
    const float* __restrict__ xz, const float* __restrict__ conv_w,
    const float* __restrict__ conv_b, float* __restrict__ xc)
{
  int idx = blockIdx.x * 256 + threadIdx.x;
  if (idx >= BL_*DI_) return;
  int d = idx & (DI_-1);
  int bl = idx >> 8;
  int l = bl & (L_-1), b = bl >> 10;
  float acc = conv_b[d];
  #pragma unroll
  for (int k=0;k<DC_;k++){
    int lk = l - (DC_-1) + k;
    if (lk >= 0)
      acc = fmaf(xz[((size_t)((b<<10)|lk))*512 + d], conv_w[d*DC_+k], acc);
  }
  xc[idx] = siluf(acc);
}

// ---------------- fused selective-scan + LSTM (independent recurrences) ----
// grid 72 x 512 threads. blocks 0..63: scan (b = blk>>3, d0 = (blk&7)*32)
//                        blocks 64..71: lstm (b = blk-64)
__global__ __launch_bounds__(512,2) void scan_lstm_kernel(
    const float* __restrict__ delta, const float* __restrict__ dbl,
    const float* __restrict__ xc, const float* __restrict__ xz,
    const float* __restrict__ A_log, const float* __restrict__ Dp,
    float* __restrict__ yg,
    const float* __restrict__ xg, const float* __restrict__ w_hh,
    float* __restrict__ HL)
{
  __shared__ float sd[32][32], sx[32][32], sz[32][32];
  __shared__ float sB[32][17], sC[32][17];
  __shared__ float lh[2][128];
  const int tid = threadIdx.x;

  if (blockIdx.x < 64){
    // ---------- selective scan ----------
    const int b = blockIdx.x >> 3;
    const int d0 = (blockIdx.x & 7) * 32;
    const int dl = tid >> 4, s = tid & 15;
    const float A = -expf(A_log[(d0+dl)*DS_ + s]);
    const float Dv = Dp[d0+dl];
    float h = 0.f;
    const size_t base = (size_t)b * L_;
    for (int t0=0; t0<L_; t0+=32){
      __syncthreads();
      #pragma unroll
      for (int i0=0;i0<2;i0++){
        int i = tid + i0*512;
        int tl = i >> 5, e = i & 31;
        size_t r = base + t0 + tl;
        sd[tl][e] = delta[r*256 + d0 + e];
        sx[tl][e] = xc[r*256 + d0 + e];
        sz[tl][e] = xz[r*512 + 256 + d0 + e];
      }
      {
        int tl = tid >> 4, e = tid & 15;
        size_t r = base + t0 + tl;
        sB[tl][e] = dbl[r*40 + DTR_ + e];
        sC[tl][e] = dbl[r*40 + DTR_ + DS_ + e];
      }
      __syncthreads();
      for (int j=0;j<32;j++){
        float dlt = sd[j][dl], xcv = sx[j][dl];
        float Bv = sB[j][s], Cv = sC[j][s];
        h = fmaf(fexpf_(dlt*A), h, (dlt*Bv)*xcv);
        float pr = h * Cv;
        pr += qbcast_xor1(pr);
        pr += qbcast_xor2(pr);
        pr += __shfl_xor(pr, 4);
        pr += __shfl_xor(pr, 8);
        if (s == 0){
          float y = pr + Dv * xcv;
          yg[(base + t0 + j)*256 + d0 + dl] = y * siluf(sz[j][dl]);
        }
      }
    }
  } else {
    // ---------- LSTM ----------
    const int b = blockIdx.x - 64;
    const int g = tid >> 2, p = tid & 3;
    float wi[32], wf[32], wg_[32], wo[32];
    #pragma unroll
    for (int jj=0;jj<8;jj++){
      const int j = (jj + 2*p) & 7;
      const float* wr = w_hh + (size_t)(32*p + 4*j)*512 + g;
      #pragma unroll
      for (int c=0;c<4;c++){
        wi [4*jj+c] = wr[(size_t)c*512];
        wf [4*jj+c] = wr[(size_t)c*512 + 128];
        wg_[4*jj+c] = wr[(size_t)c*512 + 256];
        wo [4*jj+c] = wr[(size_t)c*512 + 384];
      }
    }
    // pin weights into VGPRs: forbid rematerialization/scratch demotion
    #pragma unroll
    for (int i=0;i<32;i++)
      asm volatile("" : "+v"(wi[i]), "+v"(wf[i]), "+v"(wg_[i]), "+v"(wo[i]));
    if (tid < 128) lh[0][tid] = 0.f;
    float creg = 0.f;
    const float* xgb = xg + (size_t)b * L_ * 512;
    float* HLb = HL + (size_t)b * L_ * 128;
    float xv0 = xgb[g], xv1 = xgb[128+g], xv2 = xgb[256+g], xv3 = xgb[384+g];
    __syncthreads();
    int cur = 0;
    for (int t=0;t<L_;t++){
      const float* hb = lh[cur] + 32*p;
      float a_i=0,a_f=0,a_g=0,a_o=0;
      #pragma unroll
      for (int jj=0;jj<8;jj++){
        const int j = (jj + 2*p) & 7;   // LDS addr rotation only; reg idx static
        float4 hv = *(const float4*)(hb + 4*j);
        a_i = fmaf(hv.x, wi [4*jj+0], a_i);
        a_f = fmaf(hv.x, wf [4*jj+0], a_f);
        a_g = fmaf(hv.x, wg_[4*jj+0], a_g);
        a_o = fmaf(hv.x, wo [4*jj+0], a_o);
        a_i = fmaf(hv.y, wi [4*jj+1], a_i);
        a_f = fmaf(hv.y, wf [4*jj+1], a_f);
        a_g = fmaf(hv.y, wg_[4*jj+1], a_g);
        a_o = fmaf(hv.y, wo [4*jj+1], a_o);
        a_i = fmaf(hv.z, wi [4*jj+2], a_i);
        a_f = fmaf(hv.z, wf [4*jj+2], a_f);
        a_g = fmaf(hv.z, wg_[4*jj+2], a_g);
        a_o = fmaf(hv.z, wo [4*jj+2], a_o);
        a_i = fmaf(hv.w, wi [4*jj+3], a_i);
        a_f = fmaf(hv.w, wf [4*jj+3], a_f);
        a_g = fmaf(hv.w, wg_[4*jj+3], a_g);
        a_o = fmaf(hv.w, wo [4*jj+3], a_o);
      }
      float xn0=0.f,xn1=0.f,xn2=0.f,xn3=0.f;
      if (t+1 < L_){
        const float* xr = xgb + (size_t)(t+1)*512;
        xn0 = xr[g]; xn1 = xr[128+g]; xn2 = xr[256+g]; xn3 = xr[384+g];
      }
      a_i += qbcast_xor1(a_i); a_i += qbcast_xor2(a_i);
      a_f += qbcast_xor1(a_f); a_f += qbcast_xor2(a_f);
      a_g += qbcast_xor1(a_g); a_g += qbcast_xor2(a_g);
      a_o += qbcast_xor1(a_o); a_o += qbcast_xor2(a_o);
      // all lanes hold the full sums -> compute activations uniformly
      float c = fsig(a_f + xv1)*creg + fsig(a_i + xv0)*ftanh(a_g + xv2);
      float hval = fsig(a_o + xv3)*ftanh(c);
      creg = c;
      if (p == 0){
        lh[cur^1][g] = hval;
        HLb[t*128 + g] = hval;
      }
      __syncthreads();
      cur ^= 1;
      xv0=xn0; xv1=xn1; xv2=xn2; xv3=xn3;
    }
  }
}

// ---------------- pack attention QKV weights ----------------
__global__ __launch_bounds__(256) void pack_kernel(
    const float* __restrict__ ca_w, const float* __restrict__ ca_b,
    float* __restrict__ wpk)
{
  int idx = blockIdx.x * 256 + threadIdx.x;
  if (idx >= 49152) return;
  int in = idx / 384, c = idx % 384;
  int seg = c >> 7, o = c & 127;
  int dL = (seg==0)?0:1;
  int iL = (seg==0)?0:((seg==1)?1:2);
  int dM = (seg==2)?1:0;
  int iM = (seg==0)?1:((seg==1)?2:0);
  wpk[idx]         = ca_w[(((size_t)(dL*4+iL))*128 + in)*128 + o];
  wpk[49152 + idx] = ca_w[(((size_t)(dM*4+iM))*128 + in)*128 + o];
  if (in == 0){
    wpk[98304 + c] = ca_b[(dL*4+iL)*128 + o];
    wpk[98688 + c] = ca_b[(dM*4+iM)*128 + o];
  }
}

// ---------------- flash attention, 2-way key-split, both directions -------
// grid (4, 32, 2) x 512 threads: q = tid&255 (within 256-row tile),
// half = tid>>8 owns keys [half*512, half*512+512)
__global__ __launch_bounds__(512,2) void attn_kernel(
    const float* __restrict__ PL, const float* __restrict__ PM,
    float* __restrict__ AO)
{
  __shared__ float Kt[2][32][32];
  __shared__ float Vt[2][32][32];
  __shared__ float po[256][33];
  __shared__ float pml[256][2];
  const int tid = threadIdx.x;
  const int q = tid & 255, half = tid >> 8;
  const int dir = blockIdx.z;
  const int bh = blockIdx.y;
  const int b = bh >> 2, hh = bh & 3;
  const int qg = blockIdx.x * 256 + q;
  const float* Qb; const float* Kb; const float* Vb;
  if (dir == 0){ Qb = PL;       Kb = PM;       Vb = PM + 128; }
  else         { Qb = PM + 256; Kb = PL + 128; Vb = PL + 256; }
  const size_t rowb = (size_t)b * L_;
  float qv[32];
  {
    const float4* qp = (const float4*)(Qb + (rowb + qg)*384 + hh*32);
    #pragma unroll
    for (int j=0;j<8;j++){
      float4 v = qp[j];
      qv[4*j]=v.x; qv[4*j+1]=v.y; qv[4*j+2]=v.z; qv[4*j+3]=v.w;
    }
  }
  #pragma unroll
  for (int i=0;i<32;i++) asm volatile("" : "+v"(qv[i]));
  float o[32];
  #pragma unroll
  for (int j=0;j<32;j++) o[j]=0.f;
  float m = -1e30f, l = 0.f;
  const float scale = 0.17677669529663687f;  // 1/sqrt(32)
  const int kbase = half * 512;
  for (int k0=0;k0<512;k0+=32){
    __syncthreads();
    #pragma unroll
    for (int i0=0;i0<4;i0++){
      int i = q + i0*256;
      int r = i >> 5, c = i & 31;
      Kt[half][r][c] = Kb[(rowb + kbase + k0 + r)*384 + hh*32 + c];
      Vt[half][r][c] = Vb[(rowb + kbase + k0 + r)*384 + hh*32 + c];
    }
    __syncthreads();
    for (int kk=0;kk<32;kk++){
      float d0=0.f,d1=0.f,d2=0.f,d3=0.f;
      #pragma unroll
      for (int j=0;j<32;j+=4){
        d0 = fmaf(qv[j],   Kt[half][kk][j],   d0);
        d1 = fmaf(qv[j+1], Kt[half][kk][j+1], d1);
        d2 = fmaf(qv[j+2], Kt[half][kk][j+2], d2);
        d3 = fmaf(qv[j+3], Kt[half][kk][j+3], d3);
      }
      float s4 = ((d0+d1)+(d2+d3))*scale;
      if (s4 > m + 8.f){           // defer-max: rare rescale
        float corr = fexpf_(m - s4);
        l *= corr;
        #pragma unroll
        for (int j=0;j<32;j++) o[j] *= corr;
        m = s4;
      }
      float p = fexpf_(s4 - m);
      l += p;
      #pragma unroll
      for (int j=0;j<32;j++) o[j] = fmaf(p, Vt[half][kk][j], o[j]);
    }
  }
  if (half == 1){
    pml[q][0] = m; pml[q][1] = l;
    #pragma unroll
    for (int j=0;j<32;j++) po[q][j] = o[j];
  }
  __syncthreads();
  if (half == 0){
    float m1 = pml[q][0], l1 = pml[q][1];
    float mm = fmaxf(m, m1);
    float c0 = fexpf_(m - mm), c1 = fexpf_(m1 - mm);
    float linv = 1.f / (l*c0 + l1*c1);
    float* op = AO + (size_t)dir*BL_*128 + (rowb + qg)*128 + hh*32;
    #pragma unroll
    for (int j=0;j<32;j+=4){
      float4 v;
      v.x = (o[j]*c0   + po[q][j]*c1)  *linv;
      v.y = (o[j+1]*c0 + po[q][j+1]*c1)*linv;
      v.z = (o[j+2]*c0 + po[q][j+2]*c1)*linv;
      v.w = (o[j+3]*c0 + po[q][j+3]*c1)*linv;
      *(float4*)(op + j) = v;
    }
  }
}

// ---------------- residual + LayerNorm ----------------
__global__ __launch_bounds__(64) void ln_kernel(
    const float* __restrict__ HL, const float* __restrict__ T0,
    const float* __restrict__ HM, const float* __restrict__ T1,
    const float* __restrict__ ln_g, const float* __restrict__ ln_b,
    float* __restrict__ HLu, float* __restrict__ HMu)
{
  const int row = blockIdx.x;
  const int which = blockIdx.y;
  const float* X = which ? HM : HL;
  const float* T = which ? T1 : T0;
  const float* g = ln_g + which*128;
  const float* bb = ln_b + which*128;
  float* O = which ? HMu : HLu;
  const int lane = threadIdx.x;
  float v0 = X[(size_t)row*128 + lane]      + T[(size_t)row*128 + lane];
  float v1 = X[(size_t)row*128 + 64 + lane] + T[(size_t)row*128 + 64 + lane];
  float s = v0 + v1, s2 = v0*v0 + v1*v1;
  #pragma unroll
  for (int off=1; off<64; off<<=1){ s += __shfl_xor(s,off); s2 += __shfl_xor(s2,off); }
  float mean = s * (1.f/128.f);
  float var = s2 * (1.f/128.f) - mean*mean;
  float r = rsqrtf(var + 1e-5f);
  O[(size_t)row*128 + lane]      = (v0 - mean)*r*g[lane]      + bb[lane];
  O[(size_t)row*128 + 64 + lane] = (v1 - mean)*r*g[64+lane]   + bb[64+lane];
}

// ---------------- mean pool ----------------
__global__ __launch_bounds__(128) void pool_kernel(
    const float* __restrict__ HMu, const float* __restrict__ HLu,
    float* __restrict__ pooled)
{
  const int whichhalf = blockIdx.x;
  const int b = blockIdx.y;
  const int d = threadIdx.x;
  const float* S = whichhalf ? HLu : HMu;
  float s = 0.f;
  for (int t=0;t<L_;t++) s += S[((size_t)b*L_ + t)*128 + d];
  pooled[b*256 + whichhalf*128 + d] = s * (1.f/1024.f);
}

// ---------------- final MLP ----------------
__global__ __launch_bounds__(128) void fc_kernel(
    const float* __restrict__ pooled,
    const float* __restrict__ fc1_w, const float* __restrict__ fc1_b,
    const float* __restrict__ fc2_w, const float* __restrict__ fc2_b,
    float* __restrict__ out)
{
  const int b = blockIdx.x;
  const int j = threadIdx.x;
  __shared__ float hid[128];
  float acc = fc1_b[j];
  for (int k=0;k<256;k++) acc = fmaf(pooled[b*256 + k], fc1_w[k*128 + j], acc);
  hid[j] = fmaxf(acc, 0.f);
  __syncthreads();
  if (j < NCLS_){
    float a = fc2_b[j];
    for (int k=0;k<128;k++) a = fmaf(hid[k], fc2_w[k*NCLS_ + j], a);
    out[b*NCLS_ + j] = a;
  }
}

extern "C" void kernel_launch(void* const* d_in, const int* in_sizes, int n_in,
                              void* d_out, int out_size, void* d_ws, size_t ws_size,
                              hipStream_t stream)
{
  const float* x            = (const float*)d_in[0];
  const float* mamba_proj_w = (const float*)d_in[1];
  const float* mamba_proj_b = (const float*)d_in[2];
  const float* in_proj_w    = (const float*)d_in[3];
  const float* conv_w       = (const float*)d_in[4];
  const float* conv_b       = (const float*)d_in[5];
  const float* x_proj_w     = (const float*)d_in[6];
  const float* dt_proj_w    = (const float*)d_in[7];
  const float* dt_proj_b    = (const float*)d_in[8];
  const float* A_log        = (const float*)d_in[9];
  const float* Dp           = (const float*)d_in[10];
  const float* out_proj_w   = (const float*)d_in[11];
  const float* lstm_w_ih    = (const float*)d_in[12];
  const float* lstm_w_hh    = (const float*)d_in[13];
  const float* lstm_b       = (const float*)d_in[14];
  const float* ca_w         = (const float*)d_in[15];
  const float* ca_b         = (const float*)d_in[16];
  const float* ln_g         = (const float*)d_in[17];
  const float* ln_b         = (const float*)d_in[18];
  const float* fc1_w        = (const float*)d_in[19];
  const float* fc1_b        = (const float*)d_in[20];
  const float* fc2_w        = (const float*)d_in[21];
  const float* fc2_b        = (const float*)d_in[22];

  float* ws     = (float*)d_ws;
  float* u      = ws + OFF_U;
  float* xc     = ws + OFF_XC;
  float* dbl    = ws + OFF_DBL;
  float* delta  = ws + OFF_DELTA;
  float* yg     = ws + OFF_YG;
  float* xz     = ws + OFF_XZ;
  float* xg     = ws + OFF_XG;
  float* HM     = ws + OFF_HM;
  float* HL     = ws + OFF_HL;
  float* wpk    = ws + OFF_WPK;
  float* PLb    = ws + OFF_PL;
  float* PMb    = ws + OFF_PM;
  float* AObase = ws + OFF_AO0;
  float* AO0    = ws + OFF_AO0;
  float* AO1    = ws + OFF_AO1;
  float* T0     = ws + OFF_T0;
  float* T1     = ws + OFF_T1;
  float* HLu    = ws + OFF_HLU;
  float* HMu    = ws + OFF_HMU;
  float* pooled = ws + OFF_POOL;

  // ---- phase 1: projections for both branches ----
  gemm_kernel<<<dim3(2,128),256,0,stream>>>(x, 12, mamba_proj_w, mamba_proj_b, u, BL_, 128, 12, 0);
  gemm128_kernel<<<dim3(4,64),256,0,stream>>>(u, 128, in_proj_w, nullptr, xz, BL_, 512, 128, 0);
  conv_silu_kernel<<<dim3(BL_*DI_/256),256,0,stream>>>(xz, conv_w, conv_b, xc);
  gemm_kernel<<<dim3(1,128),256,0,stream>>>(xc, 256, x_proj_w, nullptr, dbl, BL_, 40, 256, 0);
  gemm128_kernel<<<dim3(2,64),256,0,stream>>>(dbl, 40, dt_proj_w, dt_proj_b, delta, BL_, 256, 8, 1);
  gemm_kernel<<<dim3(8,128),256,0,stream>>>(x, 12, lstm_w_ih, lstm_b, xg, BL_, 512, 12, 0);

  // ---- phase 2: both recurrences in one launch ----
  scan_lstm_kernel<<<dim3(72),512,0,stream>>>(delta, dbl, xc, xz, A_log, Dp, yg,
                                              xg, lstm_w_hh, HL);

  // ---- phase 3: cross attention ----
  gemm128_kernel<<<dim3(1,64),256,0,stream>>>(yg, 256, out_proj_w, nullptr, HM, BL_, 128, 256, 0);
  pack_kernel<<<dim3(192),256,0,stream>>>(ca_w, ca_b, wpk);
  gemm128_kernel<<<dim3(3,64),256,0,stream>>>(HL, 128, wpk,         wpk + 98304, PLb, BL_, 384, 128, 0);
  gemm128_kernel<<<dim3(3,64),256,0,stream>>>(HM, 128, wpk + 49152, wpk + 98688, PMb, BL_, 384, 128, 0);
  attn_kernel<<<dim3(4,32,2),512,0,stream>>>(PLb, PMb, AObase);
  gemm128_kernel<<<dim3(1,64),256,0,stream>>>(AO0, 128, ca_w + 3*16384, ca_b + 384, T0, BL_, 128, 128, 0);
  gemm128_kernel<<<dim3(1,64),256,0,stream>>>(AO1, 128, ca_w + 7*16384, ca_b + 896, T1, BL_, 128, 128, 0);

  // ---- phase 4: LN, pool, MLP ----
  ln_kernel<<<dim3(8192,2),64,0,stream>>>(HL, T0, HM, T1, ln_g, ln_b, HLu, HMu);
  pool_kernel<<<dim3(2,8),128,0,stream>>>(HMu, HLu, pooled);
  fc_kernel<<<dim3(8),128,0,stream>>>(pooled, fc1_w, fc1_b, fc2_w, fc2_b, (float*)d_out);
}